// Round 6
// baseline (341.974 us; speedup 1.0000x reference)
//
#include <hip/hip_runtime.h>
#include <cstdint>
#include <cstddef>

// Problem constants
constexpr int T_N = 8192;   // rows of x / out
constexpr int MM  = 4096;   // K (cols of x, cols of W)
constexpr int NN  = 4096;   // rows of W / cols of out
constexpr int S_L = 2048;
constexpr int S_R = 2048;
constexpr float EPS_ = 1e-6f;

typedef float  f32x4   __attribute__((ext_vector_type(4)));
typedef float  f32x16  __attribute__((ext_vector_type(16)));
typedef __bf16 bf16x8  __attribute__((ext_vector_type(8)));
typedef unsigned short ushort8 __attribute__((ext_vector_type(8)));

__device__ __forceinline__ unsigned short f2bf(float f) {
  unsigned int u = __float_as_uint(f);
  u += 0x7FFFu + ((u >> 16) & 1u);   // round-to-nearest-even
  return (unsigned short)(u >> 16);
}

// ---------------------------------------------------------------------------
// Kernel 1: default maps (identity)
// ---------------------------------------------------------------------------
__global__ void init_maps(float* rowC, float* rowS, int* rowP,
                          float* colC, float* colS, int* colP) {
  int i = blockIdx.x * blockDim.x + threadIdx.x;
  if (i < NN) { rowC[i] = 1.f; rowS[i] = 0.f; rowP[i] = i; }
  if (i < MM) { colC[i] = 1.f; colS[i] = 0.f; colP[i] = i; }
}

// ---------------------------------------------------------------------------
// Kernel 2: per-index rotation maps from (pairs, theta).
// ---------------------------------------------------------------------------
__global__ void build_maps(const float* __restrict__ thL, const float* __restrict__ thR,
                           const int* __restrict__ prL, const int* __restrict__ prR,
                           float* rowC, float* rowS, int* rowP,
                           float* colC, float* colS, int* colP) {
  int s = blockIdx.x * blockDim.x + threadIdx.x;
  if (s < S_L) {
    int i = prL[2*s], j = prL[2*s+1];
    float c = cosf(thL[s]), sn = sinf(thL[s]);
    rowC[i] = c; rowS[i] = -sn; rowP[i] = j;
    rowC[j] = c; rowS[j] =  sn; rowP[j] = i;
  }
  if (s < S_R) {
    int i = prR[2*s], j = prR[2*s+1];
    float c = cosf(thR[s]), sn = sinf(thR[s]);
    colC[i] = c; colS[i] = -sn; colP[i] = j;
    colC[j] = c; colS[j] =  sn; colP[j] = i;
  }
}

// ---------------------------------------------------------------------------
// Kernel 3: build W_eff row-by-row, fused row-norm, emit bf16.
// ---------------------------------------------------------------------------
__global__ __launch_bounds__(256) void build_weff(
    const float* __restrict__ W, const float* __restrict__ brn, const float* __restrict__ elm,
    const float* __restrict__ rowC, const float* __restrict__ rowS, const int* __restrict__ rowP,
    const float* __restrict__ colC, const float* __restrict__ colS, const int* __restrict__ colP,
    unsigned short* __restrict__ Wb)
{
  __shared__ __align__(16) float rA[MM];
  __shared__ __align__(16) float rB[MM];
  __shared__ __align__(16) float rE[MM];
  __shared__ float red[4];

  int n   = blockIdx.x;
  int tid = threadIdx.x;
  int pn  = rowP[n];
  float cl = rowC[n], sl = rowS[n];
  const float* Wn = W + (size_t)n  * MM;
  const float* Wp = W + (size_t)pn * MM;

  for (int m = tid * 4; m < MM; m += 1024) {
    *(f32x4*)&rA[m] = *(const f32x4*)&Wn[m];
    *(f32x4*)&rB[m] = *(const f32x4*)&Wp[m];
  }
  __syncthreads();

  float ss = 0.f;
  for (int m = tid; m < MM; m += 256) {
    int p = colP[m];
    float c = colC[m], s = colS[m];
    float e = cl * (c * rA[m] + s * rA[p]) + sl * (c * rB[m] + s * rB[p]);
    rE[m] = e;
    ss += e * e;
  }
  #pragma unroll
  for (int o = 32; o; o >>= 1) ss += __shfl_xor(ss, o);
  int lane = tid & 63, wid = tid >> 6;
  if (lane == 0) red[wid] = ss;
  __syncthreads();
  float tot = red[0] + red[1] + red[2] + red[3];
  float scale = brn[n] * expf(elm[n]) / sqrtf(tot + EPS_);

  for (int m = tid * 8; m < MM; m += 2048) {
    ushort8 pkt;
    #pragma unroll
    for (int q = 0; q < 8; q++) pkt[q] = f2bf(rE[m + q] * scale);
    *(ushort8*)&Wb[(size_t)n * MM + m] = pkt;
  }
}

// ---------------------------------------------------------------------------
// Kernel 4: x (f32) -> bf16
// ---------------------------------------------------------------------------
__global__ __launch_bounds__(256) void conv_x(const float* __restrict__ x,
                                              unsigned short* __restrict__ xb) {
  const size_t total = (size_t)T_N * MM / 8;
  for (size_t i = (size_t)blockIdx.x * 256 + threadIdx.x; i < total; i += 2048ull * 256ull) {
    const float* s = x + i * 8;
    f32x4 v0 = *(const f32x4*)s;
    f32x4 v1 = *(const f32x4*)(s + 4);
    ushort8 p;
    p[0] = f2bf(v0.x); p[1] = f2bf(v0.y); p[2] = f2bf(v0.z); p[3] = f2bf(v0.w);
    p[4] = f2bf(v1.x); p[5] = f2bf(v1.y); p[6] = f2bf(v1.z); p[7] = f2bf(v1.w);
    *(ushort8*)(xb + i * 8) = p;
  }
}

// ---------------------------------------------------------------------------
// global->LDS async staging helper (16B, linear LDS dest)
// ---------------------------------------------------------------------------
typedef const __attribute__((address_space(1))) unsigned int* as1_u32p;
typedef __attribute__((address_space(3))) unsigned int* as3_u32p;

__device__ __forceinline__ void gl_lds16(const void* g, void* l) {
  __builtin_amdgcn_global_load_lds((as1_u32p)g, (as3_u32p)l, 16, 0, 0);
}

// ---------------------------------------------------------------------------
// Kernel 5a: 256x256 GEMM, BK=64, 8 waves (2Mx4N), per-wave 128x64.
// MFMA shape: 32x32x16 bf16 (8.07 cyc/CU per 32k FLOP vs 4.85/16k for 16x16
// -> 17% lower MFMA issue floor).  Per wave per K-tile: 4 mb x 2 nb x 4 ks
// = 32 MFMA; acc[4][2] f32x16.  A/B frag: lane&31 = row/col, lane>>5 = k-half
// (8 bf16 = 16B contiguous).  C/D: col=lane&31, row=(reg&3)+8*(reg>>2)+
// 4*(lane>>5)  [m74/m101-verified].
// Pipeline (r5-verified, dup-stage removed): A 3 slots staged 2 ahead,
// B 2 slots staged 1 ahead; 1 barrier + vmcnt(4) gate per tile; lgkm ladder
// counted (4/4/4/0), never drained mid-tile. Swizzle: 16B-granule column
// XOR (row&7) on both stage-source and read addr; conflict-free (any 8
// consecutive lanes cover 8 distinct slots).
// ---------------------------------------------------------------------------
constexpr int GBM = 256, GBN = 256, GBK = 64;
constexpr int NTK = MM / GBK;              // 64 K-tiles
constexpr int ASLOT = GBM * GBK * 2;       // 32 KiB
constexpr int BSLOT = GBN * GBK * 2;       // 32 KiB

#define SB0() __builtin_amdgcn_sched_barrier(0)
#define LGKM(N) do { asm volatile("s_waitcnt lgkmcnt(" #N ")" ::: "memory"); \
                     SB0(); } while (0)

// 8 B-frag reads: bf[nb][ks]
#define RD_B8(BB)                                                             \
  _Pragma("unroll") for (int n_ = 0; n_ < 2; ++n_)                            \
  _Pragma("unroll") for (int k_ = 0; k_ < 4; ++k_)                            \
    bf[n_][k_] = *(const bf16x8*)((BB) + brow0 + n_ * 4096 + koff[k_]);

// 4 A-frag reads for one 32-row m-block
#define RD_A4(DST, AB, MB)                                                    \
  _Pragma("unroll") for (int k_ = 0; k_ < 4; ++k_)                            \
    DST[k_] = *(const bf16x8*)((AB) + arow0 + (MB) * 4096 + koff[k_]);

// 4 MFMA: acc[MB][NB] over ks
#define CL4(AF, MB, NB)                                                       \
  __builtin_amdgcn_s_setprio(1);                                              \
  _Pragma("unroll") for (int k_ = 0; k_ < 4; ++k_)                            \
    acc[MB][NB] = __builtin_amdgcn_mfma_f32_32x32x16_bf16(                    \
        AF[k_], bf[NB][k_], acc[MB][NB], 0, 0, 0);                            \
  __builtin_amdgcn_s_setprio(0);

#define STAGE_A(KOF, SL)                                                      \
  _Pragma("unroll") for (int l_ = 0; l_ < 4; ++l_)                            \
    gl_lds16(sA + (size_t)l_ * (64 * MM) + (KOF),                             \
             ldsA + (SL) * ASLOT + dstb + l_ * 8192);
#define STAGE_B(KOF, SL)                                                      \
  _Pragma("unroll") for (int l_ = 0; l_ < 4; ++l_)                            \
    gl_lds16(sB + (size_t)l_ * (64 * MM) + (KOF),                             \
             ldsB + (SL) * BSLOT + dstb + l_ * 8192);

#define GATE4 do { asm volatile("s_waitcnt vmcnt(4)" ::: "memory");           \
                   __builtin_amdgcn_s_barrier(); } while (0)
#define GATE0 do { asm volatile("s_waitcnt vmcnt(0)" ::: "memory");           \
                   __builtin_amdgcn_s_barrier(); } while (0)
#define NOGATE do { } while (0)

// ledger per tile: lgkm [B8+af0 | af1 | af2 | af3] counted 4/4/4/0;
// vm enter [A(t+1)] -> issue B(t+1),A(t+2) -> vmcnt(4) retires A(t+1),B(t+1).
#define TILE(KOF, RA, RB, WA, WB, DOB, DOA, GATE)                             \
  {                                                                           \
    const char* Ab_ = ldsA + (RA) * ASLOT;                                    \
    const char* Bb_ = ldsB + (RB) * BSLOT;                                    \
    bf16x8 bf[2][4], af0[4], af1[4], af2[4], af3[4];                          \
    RD_B8(Bb_);                                                               \
    RD_A4(af0, Ab_, 0);                                                       \
    SB0();                                                                    \
    RD_A4(af1, Ab_, 1);                                                       \
    SB0();                                                                    \
    if (DOB) { STAGE_B((KOF) + GBK, WB); }                                    \
    SB0();                                                                    \
    if (DOA) { STAGE_A((KOF) + 2 * GBK, WA); }                                \
    LGKM(4);                                                                  \
    CL4(af0, 0, 0);                                                           \
    RD_A4(af2, Ab_, 2);                                                       \
    LGKM(4);                                                                  \
    CL4(af1, 1, 0);                                                           \
    CL4(af0, 0, 1);                                                           \
    RD_A4(af3, Ab_, 3);                                                       \
    LGKM(4);                                                                  \
    CL4(af2, 2, 0);                                                           \
    CL4(af1, 1, 1);                                                           \
    LGKM(0);                                                                  \
    CL4(af3, 3, 0);                                                           \
    CL4(af2, 2, 1);                                                           \
    CL4(af3, 3, 1);                                                           \
    GATE;                                                                     \
  }

__global__ __launch_bounds__(512, 2) void gemm8(
    const unsigned short* __restrict__ xb,
    const unsigned short* __restrict__ wb,
    const float* __restrict__ bias,
    float* __restrict__ C)
{
  __shared__ __align__(16) unsigned short As[3 * GBM * GBK];  // 96 KiB
  __shared__ __align__(16) unsigned short Bs[2 * GBN * GBK];  // 64 KiB
  char* ldsA = (char*)As;
  char* ldsB = (char*)Bs;

  // grid = 512 = 32 (tm) x 16 (tn); 512 % 8 == 0 -> simple XCD swizzle
  int bid = blockIdx.x;
  int swz = (bid & 7) * 64 + (bid >> 3);
  int tn = swz & 15, tm = swz >> 4;
  const int trow0 = tm * GBM;
  const int tcol0 = tn * GBN;

  int tid  = threadIdx.x;
  int lane = tid & 63;
  int wid  = tid >> 6;
  int wr = wid >> 2, wc = wid & 3;   // wave coords: 2 x 4
  int l31 = lane & 31;               // row (A) / col (B) within 32-block
  int hi  = lane >> 5;               // k-half
  const int sw = (lane & 7) << 4;    // swizzle byte term (row&7 == lane&7)
  const int arow0 = (wr * 128 + l31) * 128;  // A row base bytes
  const int brow0 = (wc * 64  + l31) * 128;  // B row base bytes
  int koff[4];
  #pragma unroll
  for (int k_ = 0; k_ < 4; ++k_) koff[k_] = (k_ * 32 + hi * 16) ^ sw;

  // staging geometry: 4 granules/thread/operand; row r0+64*l, const col group
  const int r0   = tid >> 3;
  const int colg = (tid & 7) ^ (r0 & 7);
  const unsigned short* sA = xb + (size_t)(trow0 + r0) * MM + colg * 8;
  const unsigned short* sB = wb + (size_t)(tcol0 + r0) * MM + colg * 8;
  const int dstb = tid * 16;

  f32x16 acc[4][2];
  #pragma unroll
  for (int i = 0; i < 4; i++)
    #pragma unroll
    for (int j = 0; j < 2; j++)
      #pragma unroll
      for (int q = 0; q < 16; q++) acc[i][j][q] = 0.f;

  // ---- prologue: stage B0,A0 | A1; vmcnt(4) retires B0,A0; barrier ----
  STAGE_B(0, 0);
  STAGE_A(0, 0);
  SB0();
  STAGE_A(GBK, 1);
  asm volatile("s_waitcnt vmcnt(4)" ::: "memory");
  __builtin_amdgcn_s_barrier();

  // ---- main loop: tiles 0..59, slot period 6 = lcm(3,2) ----
  int kof = 0;
  #pragma unroll 1
  for (int tb = 0; tb < NTK - 4; tb += 6) {
    TILE(kof      , 0, 0, 2, 1, 1, 1, GATE4);
    TILE(kof +  64, 1, 1, 0, 0, 1, 1, GATE4);
    TILE(kof + 128, 2, 0, 1, 1, 1, 1, GATE4);
    TILE(kof + 192, 0, 1, 2, 0, 1, 1, GATE4);
    TILE(kof + 256, 1, 0, 0, 1, 1, 1, GATE4);
    TILE(kof + 320, 2, 1, 1, 0, 1, 1, GATE4);
    kof += 384;
  }
  // ---- tail tiles 60..63 ----
  TILE(kof      , 0, 0, 2, 1, 1, 1, GATE4);   // t=60: B61->s1, A62->s2
  TILE(kof +  64, 1, 1, 0, 0, 1, 1, GATE4);   // t=61: B62->s0, A63->s0
  TILE(kof + 128, 2, 0, 0, 1, 1, 0, GATE0);   // t=62: B63->s1 only
  TILE(kof + 192, 0, 1, 0, 0, 0, 0, NOGATE);  // t=63

  // ---- epilogue: C/D 32x32: col=lane&31, row=(reg&3)+8*(reg>>2)+4*hi ----
  #pragma unroll
  for (int nb = 0; nb < 2; ++nb) {
    int col = tcol0 + wc * 64 + nb * 32 + l31;
    float bi = bias[col];
    #pragma unroll
    for (int mb = 0; mb < 4; ++mb) {
      int row0 = trow0 + wr * 128 + mb * 32 + 4 * hi;
      #pragma unroll
      for (int rg = 0; rg < 16; ++rg) {
        int row = row0 + (rg & 3) + 8 * (rg >> 2);
        C[(size_t)row * NN + col] = acc[mb][nb][rg] + bi;
      }
    }
  }
}

// ---------------------------------------------------------------------------
// Kernel 5b (fallback, ws too small for xb): m97-style 128x128 GEMM with
// inline f32->bf16 A-staging.
// ---------------------------------------------------------------------------
constexpr int BM = 128, BN = 128, BK = 64;

__global__ __launch_bounds__(256) void gemm_fb(
    const float* __restrict__ xf,
    const unsigned short* __restrict__ wb, const float* __restrict__ bias,
    float* __restrict__ C)
{
  __shared__ __align__(16) unsigned short As2[BM * BK];
  __shared__ __align__(16) unsigned short Bs2[BN * BK];

  int bid = blockIdx.x;
  int swz = (bid & 7) * 256 + (bid >> 3);
  int tn = swz & 31;
  int tm = swz >> 5;

  int tid  = threadIdx.x;
  int lane = tid & 63;
  int wid  = tid >> 6;
  int wr = wid >> 1, wc = wid & 1;
  int lr = lane & 15;
  int lg = lane >> 4;

  f32x4 acc[4][4];
  #pragma unroll
  for (int i = 0; i < 4; i++)
    #pragma unroll
    for (int j = 0; j < 4; j++) {
      f32x4 z = {0.f, 0.f, 0.f, 0.f};
      acc[i][j] = z;
    }

  int srow = tid >> 3;
  int scol = (tid & 7) * 8;
  const size_t a_base = (size_t)(tm * BM) * MM;
  const size_t b_base = (size_t)(tn * BN) * MM;

  for (int k0 = 0; k0 < MM; k0 += BK) {
    #pragma unroll
    for (int c = 0; c < 4; c++) {
      int row = c * 32 + srow;
      gl_lds16(wb + b_base + (size_t)row * MM + k0 + scol,
               (char*)Bs2 + (c * 256 + wid * 64) * 16);
    }
    #pragma unroll
    for (int c = 0; c < 4; c++) {
      int row = c * 32 + srow;
      const float* s = xf + a_base + (size_t)row * MM + k0 + scol;
      f32x4 v0 = *(const f32x4*)s;
      f32x4 v1 = *(const f32x4*)(s + 4);
      ushort8 p;
      p[0] = f2bf(v0.x); p[1] = f2bf(v0.y); p[2] = f2bf(v0.z); p[3] = f2bf(v0.w);
      p[4] = f2bf(v1.x); p[5] = f2bf(v1.y); p[6] = f2bf(v1.z); p[7] = f2bf(v1.w);
      *(ushort8*)&As2[(c * 256 + tid) * 8] = p;
    }
    __syncthreads();

    #pragma unroll
    for (int kk = 0; kk < 2; kk++) {
      bf16x8 a[4], b[4];
      #pragma unroll
      for (int i = 0; i < 4; i++) {
        a[i] = *(const bf16x8*)&As2[(wr * 64 + i * 16 + lr) * BK + kk * 32 + lg * 8];
        b[i] = *(const bf16x8*)&Bs2[(wc * 64 + i * 16 + lr) * BK + kk * 32 + lg * 8];
      }
      #pragma unroll
      for (int i = 0; i < 4; i++)
        #pragma unroll
        for (int j = 0; j < 4; j++)
          acc[i][j] = __builtin_amdgcn_mfma_f32_16x16x32_bf16(a[i], b[j], acc[i][j], 0, 0, 0);
    }
    __syncthreads();
  }

  int gn0 = tn * BN + wc * 64;
  int gt0 = tm * BM + wr * 64;
  #pragma unroll
  for (int j = 0; j < 4; j++) {
    int gn = gn0 + j * 16 + lr;
    float bi = bias[gn];
    #pragma unroll
    for (int i = 0; i < 4; i++) {
      int t0 = gt0 + i * 16 + lg * 4;
      #pragma unroll
      for (int q = 0; q < 4; q++)
        C[(size_t)(t0 + q) * NN + gn] = acc[i][j][q] + bi;
    }
  }
}

// ---------------------------------------------------------------------------
extern "C" void kernel_launch(void* const* d_in, const int* in_sizes, int n_in,
                              void* d_out, int out_size, void* d_ws, size_t ws_size,
                              hipStream_t stream)
{
  const float* x    = (const float*)d_in[0];
  const float* W    = (const float*)d_in[1];
  const float* bias = (const float*)d_in[2];
  const float* thL  = (const float*)d_in[3];
  const float* thR  = (const float*)d_in[4];
  const float* elm  = (const float*)d_in[5];
  const float* brn  = (const float*)d_in[6];
  const int*   prL  = (const int*)d_in[7];
  const int*   prR  = (const int*)d_in[8];
  float* out = (float*)d_out;

  char* ws = (char*)d_ws;
  unsigned short* Wb = (unsigned short*)ws;          // N*M bf16 = 33.5 MB
  size_t off = (size_t)NN * MM * 2;
  float* rowC = (float*)(ws + off); off += NN * 4;
  float* rowS = (float*)(ws + off); off += NN * 4;
  int*   rowP = (int*)  (ws + off); off += NN * 4;
  float* colC = (float*)(ws + off); off += MM * 4;
  float* colS = (float*)(ws + off); off += MM * 4;
  int*   colP = (int*)  (ws + off); off += MM * 4;
  unsigned short* xb = (unsigned short*)(ws + off);  // T*M bf16 = 67 MB
  bool use_xb = ws_size >= off + (size_t)T_N * MM * 2;

  init_maps <<<16, 256, 0, stream>>>(rowC, rowS, rowP, colC, colS, colP);
  build_maps<<< 8, 256, 0, stream>>>(thL, thR, prL, prR, rowC, rowS, rowP, colC, colS, colP);
  build_weff<<<NN, 256, 0, stream>>>(W, brn, elm, rowC, rowS, rowP, colC, colS, colP, Wb);

  if (use_xb) {
    conv_x<<<2048, 256, 0, stream>>>(x, xb);
    gemm8<<<512, 512, 0, stream>>>(xb, Wb, bias, out);
  } else {
    gemm_fb<<<2048, 256, 0, stream>>>(x, Wb, bias, out);
  }
}

// Round 7
// 320.368 us; speedup vs baseline: 1.0674x; 1.0674x over previous
//
#include <hip/hip_runtime.h>
#include <cstdint>
#include <cstddef>

// Problem constants
constexpr int T_N = 8192;   // rows of x / out
constexpr int MM  = 4096;   // K (cols of x, cols of W)
constexpr int NN  = 4096;   // rows of W / cols of out
constexpr int S_L = 2048;
constexpr int S_R = 2048;
constexpr float EPS_ = 1e-6f;

typedef float  f32x4   __attribute__((ext_vector_type(4)));
typedef __bf16 bf16x8  __attribute__((ext_vector_type(8)));
typedef unsigned short ushort8 __attribute__((ext_vector_type(8)));

__device__ __forceinline__ unsigned short f2bf(float f) {
  unsigned int u = __float_as_uint(f);
  u += 0x7FFFu + ((u >> 16) & 1u);   // round-to-nearest-even
  return (unsigned short)(u >> 16);
}

// ---------------------------------------------------------------------------
// Kernel 1: identity column maps
// ---------------------------------------------------------------------------
__global__ void init_cols(float* colC, float* colS, int* colP) {
  int i = blockIdx.x * blockDim.x + threadIdx.x;
  if (i < MM) { colC[i] = 1.f; colS[i] = 0.f; colP[i] = i; }
}

// ---------------------------------------------------------------------------
// Kernel 2: column rotation maps from (pairs_R, theta_R).
// ---------------------------------------------------------------------------
__global__ void build_cols(const float* __restrict__ thR, const int* __restrict__ prR,
                           float* colC, float* colS, int* colP) {
  int s = blockIdx.x * blockDim.x + threadIdx.x;
  if (s < S_R) {
    int i = prR[2*s], j = prR[2*s+1];
    float c = cosf(thR[s]), sn = sinf(thR[s]);
    colC[i] = c; colS[i] = -sn; colP[i] = j;
    colC[j] = c; colS[j] =  sn; colP[j] = i;
  }
}

// ---------------------------------------------------------------------------
// Kernel 3: build W_eff PAIR-wise: block s handles rows i=prL[2s], j=prL[2s+1].
// Both output rows derive from the same two source rows -> W read once.
//   vi = cR*Wi[m] + sR*Wi[p];  vj likewise
//   ei = cl*vi - sl*vj;  ej = sl*vi + cl*vj   (row rotation)
//   scale_r = brn[r]*exp(elm[r])/sqrt(sum e^2 + EPS);  Wb[r] = bf16(e*scale)
// ---------------------------------------------------------------------------
__global__ __launch_bounds__(256) void weff_pair(
    const float* __restrict__ W, const float* __restrict__ brn, const float* __restrict__ elm,
    const float* __restrict__ thL, const int* __restrict__ prL,
    const float* __restrict__ colC, const float* __restrict__ colS, const int* __restrict__ colP,
    unsigned short* __restrict__ Wb)
{
  __shared__ __align__(16) float rI[MM];
  __shared__ __align__(16) float rJ[MM];
  __shared__ float red[8];

  int s   = blockIdx.x;
  int tid = threadIdx.x;
  int i = prL[2*s], j = prL[2*s+1];
  float cl = cosf(thL[s]), sl = sinf(thL[s]);
  const float* Wi = W + (size_t)i * MM;
  const float* Wj = W + (size_t)j * MM;

  for (int m = tid * 4; m < MM; m += 1024) {
    *(f32x4*)&rI[m] = *(const f32x4*)&Wi[m];
    *(f32x4*)&rJ[m] = *(const f32x4*)&Wj[m];
  }
  __syncthreads();

  float ssi = 0.f, ssj = 0.f;
  for (int m = tid; m < MM; m += 256) {
    int p = colP[m];
    float c = colC[m], sn = colS[m];
    float vi = c * rI[m] + sn * rI[p];
    float vj = c * rJ[m] + sn * rJ[p];
    float ei = cl * vi - sl * vj;
    float ej = sl * vi + cl * vj;
    ssi += ei * ei;
    ssj += ej * ej;
  }
  #pragma unroll
  for (int o = 32; o; o >>= 1) { ssi += __shfl_xor(ssi, o); ssj += __shfl_xor(ssj, o); }
  int lane = tid & 63, wid = tid >> 6;
  if (lane == 0) { red[wid] = ssi; red[4 + wid] = ssj; }
  __syncthreads();
  float ti = red[0] + red[1] + red[2] + red[3];
  float tj = red[4] + red[5] + red[6] + red[7];
  float sci = brn[i] * expf(elm[i]) / sqrtf(ti + EPS_);
  float scj = brn[j] * expf(elm[j]) / sqrtf(tj + EPS_);

  for (int m0 = tid * 8; m0 < MM; m0 += 2048) {
    ushort8 pi, pj;
    #pragma unroll
    for (int q = 0; q < 8; q++) {
      int m = m0 + q;
      int p = colP[m];
      float c = colC[m], sn = colS[m];
      float vi = c * rI[m] + sn * rI[p];
      float vj = c * rJ[m] + sn * rJ[p];
      pi[q] = f2bf((cl * vi - sl * vj) * sci);
      pj[q] = f2bf((sl * vi + cl * vj) * scj);
    }
    *(ushort8*)&Wb[(size_t)i * MM + m0] = pi;
    *(ushort8*)&Wb[(size_t)j * MM + m0] = pj;
  }
}

// ---------------------------------------------------------------------------
// Kernel 4: x (f32) -> bf16
// ---------------------------------------------------------------------------
__global__ __launch_bounds__(256) void conv_x(const float* __restrict__ x,
                                              unsigned short* __restrict__ xb) {
  const size_t total = (size_t)T_N * MM / 8;
  for (size_t i = (size_t)blockIdx.x * 256 + threadIdx.x; i < total; i += 2048ull * 256ull) {
    const float* s = x + i * 8;
    f32x4 v0 = *(const f32x4*)s;
    f32x4 v1 = *(const f32x4*)(s + 4);
    ushort8 p;
    p[0] = f2bf(v0.x); p[1] = f2bf(v0.y); p[2] = f2bf(v0.z); p[3] = f2bf(v0.w);
    p[4] = f2bf(v1.x); p[5] = f2bf(v1.y); p[6] = f2bf(v1.z); p[7] = f2bf(v1.w);
    *(ushort8*)(xb + i * 8) = p;
  }
}

// ---------------------------------------------------------------------------
// global->LDS async staging helper (16B, linear LDS dest)
// ---------------------------------------------------------------------------
typedef const __attribute__((address_space(1))) unsigned int* as1_u32p;
typedef __attribute__((address_space(3))) unsigned int* as3_u32p;

__device__ __forceinline__ void gl_lds16(const void* g, void* l) {
  __builtin_amdgcn_global_load_lds((as1_u32p)g, (as3_u32p)l, 16, 0, 0);
}

// ---------------------------------------------------------------------------
// Kernel 5a: 256x256 GEMM — faithful m201 8-phase schedule.
//   BK=64, 8 waves (2Mx4N), per-wave 128x64, acc[8][4], 16x16x32 bf16 MFMA.
//   LDS 128 KiB: dbuf x (A 256x64 + B 256x64); half-tile = 128 rows = 16 KiB
//   = 2 gl_lds/thread.  Per K-tile, 4 phases, each:
//     {ds_reads, maybe stage 1-2 half-tiles} -> [lgkm(8) if 12 reads] ->
//     barrier -> lgkm(0)+sched_barrier -> setprio(1), 16 MFMA, setprio(0)
//     -> barrier.
//   Stages: p1: B1(t+1)->buf^1 ; p3: A0(t+2)->buf ; p4: A1(t+2)+B0(t+2)->buf,
//   then vmcnt(6) (= 3 half-tiles in flight; never 0 until tail).
//   Quadrants: p1 (mi0-3 x ni0-1), p2 (mi4-7 x ni0-1), p3 (mi4-7 x ni2-3),
//   p4 (mi0-3 x ni2-3) — every staged region last-read >= 1 barrier earlier.
//   Swizzle (r2/r5-verified, conflict-free): stage src col-group ^= (row&7);
//   read byte addr: row*128 + ((kk*64+lg*16) ^ ((lr&7)<<4)).
// ---------------------------------------------------------------------------
constexpr int GBM = 256, GBN = 256, GBK = 64;
constexpr int NTK = MM / GBK;              // 64 K-tiles
constexpr int BUFB = GBM * GBK * 2;        // 32 KiB per operand per buffer

#define SB0() __builtin_amdgcn_sched_barrier(0)
#define BAR() __builtin_amdgcn_s_barrier()
#define LGKM(N) do { asm volatile("s_waitcnt lgkmcnt(" #N ")" ::: "memory"); \
                     SB0(); } while (0)

#define RD_A8(DST, AB, MIH)                                                   \
  _Pragma("unroll") for (int i_ = 0; i_ < 4; ++i_)                            \
  _Pragma("unroll") for (int k_ = 0; k_ < 2; ++k_)                            \
    DST[i_][k_] = *(const bf16x8*)((AB) + arow0 + ((MIH) * 4 + i_) * 2048     \
                                    + ((k_ * 64 + lg * 16) ^ sw));

#define RD_B4(DST, BB, NIH)                                                   \
  _Pragma("unroll") for (int n_ = 0; n_ < 2; ++n_)                            \
  _Pragma("unroll") for (int k_ = 0; k_ < 2; ++k_)                            \
    DST[n_][k_] = *(const bf16x8*)((BB) + brow0 + ((NIH) * 2 + n_) * 2048     \
                                    + ((k_ * 64 + lg * 16) ^ sw));

#define QMF(AF, BF, MI0, NI0)                                                 \
  __builtin_amdgcn_s_setprio(1);                                              \
  _Pragma("unroll") for (int k_ = 0; k_ < 2; ++k_)                            \
  _Pragma("unroll") for (int i_ = 0; i_ < 4; ++i_)                            \
  _Pragma("unroll") for (int n_ = 0; n_ < 2; ++n_)                            \
    acc[(MI0) + i_][(NI0) + n_] = __builtin_amdgcn_mfma_f32_16x16x32_bf16(    \
        AF[i_][k_], BF[n_][k_], acc[(MI0) + i_][(NI0) + n_], 0, 0, 0);        \
  __builtin_amdgcn_s_setprio(0);

#define STG_A(KOF, BUF, H)                                                    \
  _Pragma("unroll") for (int l_ = 2 * (H); l_ < 2 * (H) + 2; ++l_)            \
    gl_lds16(sA + (size_t)l_ * (64 * MM) + (KOF),                             \
             ldsA + (BUF) * BUFB + dstb + l_ * 8192);
#define STG_B(KOF, BUF, H)                                                    \
  _Pragma("unroll") for (int l_ = 2 * (H); l_ < 2 * (H) + 2; ++l_)            \
    gl_lds16(sB + (size_t)l_ * (64 * MM) + (KOF),                             \
             ldsB + (BUF) * BUFB + dstb + l_ * 8192);

#define GATE6  asm volatile("s_waitcnt vmcnt(6)" ::: "memory")
#define GATE0v asm volatile("s_waitcnt vmcnt(0)" ::: "memory")
#define GNONE  do { } while (0)

#define TILE8(T, BB, DOB1, DOA2, GATEK)                                       \
  {                                                                           \
    const char* Ab_ = ldsA + (BB) * BUFB;                                     \
    const char* Bb_ = ldsB + (BB) * BUFB;                                     \
    bf16x8 afA[4][2], afB[4][2], bfA[2][2], bfB[2][2];                        \
    /* ---- phase 1: A-half(MIH0) + B-half(NIH0); stage B1(t+1) ---- */       \
    RD_A8(afA, Ab_, 0);                                                       \
    RD_B4(bfA, Bb_, 0);                                                       \
    if (DOB1) { STG_B(((T) + 1) * GBK, (BB) ^ 1, 1); }                        \
    LGKM(8);                                                                  \
    BAR();                                                                    \
    LGKM(0);                                                                  \
    QMF(afA, bfA, 0, 0);                                                      \
    BAR();                                                                    \
    /* ---- phase 2: A-half(MIH1) ---- */                                     \
    RD_A8(afB, Ab_, 1);                                                       \
    BAR();                                                                    \
    LGKM(0);                                                                  \
    QMF(afB, bfA, 4, 0);                                                      \
    BAR();                                                                    \
    /* ---- phase 3: B-half(NIH1); stage A0(t+2) ---- */                      \
    RD_B4(bfB, Bb_, 1);                                                       \
    if (DOA2) { STG_A(((T) + 2) * GBK, (BB), 0); }                            \
    BAR();                                                                    \
    LGKM(0);                                                                  \
    QMF(afB, bfB, 4, 2);                                                      \
    BAR();                                                                    \
    /* ---- phase 4: stage A1(t+2)+B0(t+2); counted vm gate ---- */           \
    if (DOA2) { STG_A(((T) + 2) * GBK, (BB), 1);                              \
                STG_B(((T) + 2) * GBK, (BB), 0); }                            \
    GATEK;                                                                    \
    BAR();                                                                    \
    QMF(afA, bfB, 0, 2);                                                      \
    BAR();                                                                    \
  }

__global__ __launch_bounds__(512, 2) void gemm8(
    const unsigned short* __restrict__ xb,
    const unsigned short* __restrict__ wb,
    const float* __restrict__ bias,
    float* __restrict__ C)
{
  __shared__ __align__(16) unsigned short As[2 * GBM * GBK];  // 64 KiB
  __shared__ __align__(16) unsigned short Bs[2 * GBN * GBK];  // 64 KiB
  char* ldsA = (char*)As;
  char* ldsB = (char*)Bs;

  // grid = 512 = 32 (tm) x 16 (tn); 512 % 8 == 0 -> simple XCD swizzle
  int bid = blockIdx.x;
  int swz = (bid & 7) * 64 + (bid >> 3);
  int tn = swz & 15, tm = swz >> 4;
  const int trow0 = tm * GBM;
  const int tcol0 = tn * GBN;

  int tid  = threadIdx.x;
  int lane = tid & 63;
  int wid  = tid >> 6;
  int wr = wid >> 2, wc = wid & 3;   // wave coords: 2 x 4
  int lr = lane & 15;                // fragment row/col
  int lg = lane >> 4;                // k-group (8 bf16 = 16B)
  const int sw = (lr & 7) << 4;      // swizzle byte term
  const int arow0 = (wr * 128 + lr) * 128;  // A row base bytes
  const int brow0 = (wc * 64  + lr) * 128;  // B row base bytes

  // staging geometry: granule l covers rows r0 + 64*l; const col group
  const int r0   = tid >> 3;
  const int colg = (tid & 7) ^ (r0 & 7);
  const unsigned short* sA = xb + (size_t)(trow0 + r0) * MM + colg * 8;
  const unsigned short* sB = wb + (size_t)(tcol0 + r0) * MM + colg * 8;
  const int dstb = tid * 16;

  f32x4 acc[8][4];
  #pragma unroll
  for (int i = 0; i < 8; i++)
    #pragma unroll
    for (int j = 0; j < 4; j++) {
      f32x4 z = {0.f, 0.f, 0.f, 0.f};
      acc[i][j] = z;
    }

  // ---- prologue: t0 all 4 halves -> buf0; t1 A0,A1,B0 -> buf1 ----
  STG_A(0, 0, 0); STG_A(0, 0, 1); STG_B(0, 0, 0); STG_B(0, 0, 1);
  STG_A(GBK, 1, 0); STG_A(GBK, 1, 1); STG_B(GBK, 1, 0);
  asm volatile("s_waitcnt vmcnt(6)" ::: "memory");  // retire t0; t1 in flight
  __builtin_amdgcn_s_barrier();

  // ---- main loop: tiles 0..61 ----
  #pragma unroll 1
  for (int t = 0; t < NTK - 2; t += 2) {
    TILE8(t,     0, 1, 1, GATE6);
    TILE8(t + 1, 1, 1, 1, GATE6);
  }
  // ---- tail: tile 62 (stage B1(63) only, drain), tile 63 (compute only) ----
  TILE8(NTK - 2, 0, 1, 0, GATE0v);
  TILE8(NTK - 1, 1, 0, 0, GNONE);

  // ---- epilogue: C/D layout col = lane&15, row = (lane>>4)*4 + reg ----
  #pragma unroll
  for (int ni = 0; ni < 4; ++ni) {
    int col = tcol0 + wc * 64 + ni * 16 + lr;
    float bi = bias[col];
    #pragma unroll
    for (int mi = 0; mi < 8; ++mi) {
      int rr0 = trow0 + wr * 128 + mi * 16 + lg * 4;
      #pragma unroll
      for (int qq = 0; qq < 4; ++qq)
        C[(size_t)(rr0 + qq) * NN + col] = acc[mi][ni][qq] + bi;
    }
  }
}

// ---------------------------------------------------------------------------
// Kernel 5b (fallback, ws too small for xb): m97-style 128x128 GEMM with
// inline f32->bf16 A-staging.  (Needs row maps built the old way; uses
// weff_pair output all the same since Wb is identical.)
// ---------------------------------------------------------------------------
constexpr int BM = 128, BN = 128, BK = 64;

__global__ __launch_bounds__(256) void gemm_fb(
    const float* __restrict__ xf,
    const unsigned short* __restrict__ wb, const float* __restrict__ bias,
    float* __restrict__ C)
{
  __shared__ __align__(16) unsigned short As2[BM * BK];
  __shared__ __align__(16) unsigned short Bs2[BN * BK];

  int bid = blockIdx.x;
  int swz = (bid & 7) * 256 + (bid >> 3);
  int tn = swz & 31;
  int tm = swz >> 5;

  int tid  = threadIdx.x;
  int lane = tid & 63;
  int wid  = tid >> 6;
  int wr = wid >> 1, wc = wid & 1;
  int lr = lane & 15;
  int lg = lane >> 4;

  f32x4 acc[4][4];
  #pragma unroll
  for (int i = 0; i < 4; i++)
    #pragma unroll
    for (int j = 0; j < 4; j++) {
      f32x4 z = {0.f, 0.f, 0.f, 0.f};
      acc[i][j] = z;
    }

  int srow = tid >> 3;
  int scol = (tid & 7) * 8;
  const size_t a_base = (size_t)(tm * BM) * MM;
  const size_t b_base = (size_t)(tn * BN) * MM;

  for (int k0 = 0; k0 < MM; k0 += BK) {
    #pragma unroll
    for (int c = 0; c < 4; c++) {
      int row = c * 32 + srow;
      gl_lds16(wb + b_base + (size_t)row * MM + k0 + scol,
               (char*)Bs2 + (c * 256 + wid * 64) * 16);
    }
    #pragma unroll
    for (int c = 0; c < 4; c++) {
      int row = c * 32 + srow;
      const float* s = xf + a_base + (size_t)row * MM + k0 + scol;
      f32x4 v0 = *(const f32x4*)s;
      f32x4 v1 = *(const f32x4*)(s + 4);
      ushort8 p;
      p[0] = f2bf(v0.x); p[1] = f2bf(v0.y); p[2] = f2bf(v0.z); p[3] = f2bf(v0.w);
      p[4] = f2bf(v1.x); p[5] = f2bf(v1.y); p[6] = f2bf(v1.z); p[7] = f2bf(v1.w);
      *(ushort8*)&As2[(c * 256 + tid) * 8] = p;
    }
    __syncthreads();

    #pragma unroll
    for (int kk = 0; kk < 2; kk++) {
      bf16x8 a[4], b[4];
      #pragma unroll
      for (int i = 0; i < 4; i++) {
        a[i] = *(const bf16x8*)&As2[(wr * 64 + i * 16 + lr) * BK + kk * 32 + lg * 8];
        b[i] = *(const bf16x8*)&Bs2[(wc * 64 + i * 16 + lr) * BK + kk * 32 + lg * 8];
      }
      #pragma unroll
      for (int i = 0; i < 4; i++)
        #pragma unroll
        for (int j = 0; j < 4; j++)
          acc[i][j] = __builtin_amdgcn_mfma_f32_16x16x32_bf16(a[i], b[j], acc[i][j], 0, 0, 0);
    }
    __syncthreads();
  }

  int gn0 = tn * BN + wc * 64;
  int gt0 = tm * BM + wr * 64;
  #pragma unroll
  for (int j = 0; j < 4; j++) {
    int gn = gn0 + j * 16 + lr;
    float bi = bias[gn];
    #pragma unroll
    for (int i = 0; i < 4; i++) {
      int t0 = gt0 + i * 16 + lg * 4;
      #pragma unroll
      for (int q = 0; q < 4; q++)
        C[(size_t)(t0 + q) * NN + gn] = acc[i][j][q] + bi;
    }
  }
}

// ---------------------------------------------------------------------------
extern "C" void kernel_launch(void* const* d_in, const int* in_sizes, int n_in,
                              void* d_out, int out_size, void* d_ws, size_t ws_size,
                              hipStream_t stream)
{
  const float* x    = (const float*)d_in[0];
  const float* W    = (const float*)d_in[1];
  const float* bias = (const float*)d_in[2];
  const float* thL  = (const float*)d_in[3];
  const float* thR  = (const float*)d_in[4];
  const float* elm  = (const float*)d_in[5];
  const float* brn  = (const float*)d_in[6];
  const int*   prL  = (const int*)d_in[7];
  const int*   prR  = (const int*)d_in[8];
  float* out = (float*)d_out;

  char* ws = (char*)d_ws;
  unsigned short* Wb = (unsigned short*)ws;          // N*M bf16 = 33.5 MB
  size_t off = (size_t)NN * MM * 2;
  float* colC = (float*)(ws + off); off += MM * 4;
  float* colS = (float*)(ws + off); off += MM * 4;
  int*   colP = (int*)  (ws + off); off += MM * 4;
  unsigned short* xb = (unsigned short*)(ws + off);  // T*M bf16 = 67 MB
  bool use_xb = ws_size >= off + (size_t)T_N * MM * 2;

  init_cols <<<16, 256, 0, stream>>>(colC, colS, colP);
  build_cols<<< 8, 256, 0, stream>>>(thR, prR, colC, colS, colP);
  weff_pair <<<S_L, 256, 0, stream>>>(W, brn, elm, thL, prL, colC, colS, colP, Wb);

  if (use_xb) {
    conv_x<<<2048, 256, 0, stream>>>(x, xb);
    gemm8<<<512, 512, 0, stream>>>(xb, Wb, bias, out);
  } else {
    gemm_fb<<<2048, 256, 0, stream>>>(x, Wb, bias, out);
  }
}

// Round 8
// 318.097 us; speedup vs baseline: 1.0751x; 1.0071x over previous
//
#include <hip/hip_runtime.h>
#include <cstdint>
#include <cstddef>

// Problem constants
constexpr int T_N = 8192;   // rows of x / out
constexpr int MM  = 4096;   // K (cols of x, cols of W)
constexpr int NN  = 4096;   // rows of W / cols of out
constexpr int S_L = 2048;
constexpr int S_R = 2048;
constexpr float EPS_ = 1e-6f;

typedef float  f32x4   __attribute__((ext_vector_type(4)));
typedef __bf16 bf16x8  __attribute__((ext_vector_type(8)));
typedef unsigned short ushort8 __attribute__((ext_vector_type(8)));

__device__ __forceinline__ unsigned short f2bf(float f) {
  unsigned int u = __float_as_uint(f);
  u += 0x7FFFu + ((u >> 16) & 1u);   // round-to-nearest-even
  return (unsigned short)(u >> 16);
}

// ---------------------------------------------------------------------------
// Kernel 1: identity column maps
// ---------------------------------------------------------------------------
__global__ void init_cols(float* colC, float* colS, int* colP) {
  int i = blockIdx.x * blockDim.x + threadIdx.x;
  if (i < MM) { colC[i] = 1.f; colS[i] = 0.f; colP[i] = i; }
}

// ---------------------------------------------------------------------------
// Kernel 2: column rotation maps from (pairs_R, theta_R).
// ---------------------------------------------------------------------------
__global__ void build_cols(const float* __restrict__ thR, const int* __restrict__ prR,
                           float* colC, float* colS, int* colP) {
  int s = blockIdx.x * blockDim.x + threadIdx.x;
  if (s < S_R) {
    int i = prR[2*s], j = prR[2*s+1];
    float c = cosf(thR[s]), sn = sinf(thR[s]);
    colC[i] = c; colS[i] = -sn; colP[i] = j;
    colC[j] = c; colS[j] =  sn; colP[j] = i;
  }
}

// ---------------------------------------------------------------------------
// Kernel 3: build W_eff PAIR-wise (rows i,j of a pair from the same 2 source
// rows; W read once), fused row-norm, emit bf16.
// ---------------------------------------------------------------------------
__global__ __launch_bounds__(256) void weff_pair(
    const float* __restrict__ W, const float* __restrict__ brn, const float* __restrict__ elm,
    const float* __restrict__ thL, const int* __restrict__ prL,
    const float* __restrict__ colC, const float* __restrict__ colS, const int* __restrict__ colP,
    unsigned short* __restrict__ Wb)
{
  __shared__ __align__(16) float rI[MM];
  __shared__ __align__(16) float rJ[MM];
  __shared__ float red[8];

  int s   = blockIdx.x;
  int tid = threadIdx.x;
  int i = prL[2*s], j = prL[2*s+1];
  float cl = cosf(thL[s]), sl = sinf(thL[s]);
  const float* Wi = W + (size_t)i * MM;
  const float* Wj = W + (size_t)j * MM;

  for (int m = tid * 4; m < MM; m += 1024) {
    *(f32x4*)&rI[m] = *(const f32x4*)&Wi[m];
    *(f32x4*)&rJ[m] = *(const f32x4*)&Wj[m];
  }
  __syncthreads();

  float ssi = 0.f, ssj = 0.f;
  for (int m = tid; m < MM; m += 256) {
    int p = colP[m];
    float c = colC[m], sn = colS[m];
    float vi = c * rI[m] + sn * rI[p];
    float vj = c * rJ[m] + sn * rJ[p];
    float ei = cl * vi - sl * vj;
    float ej = sl * vi + cl * vj;
    ssi += ei * ei;
    ssj += ej * ej;
  }
  #pragma unroll
  for (int o = 32; o; o >>= 1) { ssi += __shfl_xor(ssi, o); ssj += __shfl_xor(ssj, o); }
  int lane = tid & 63, wid = tid >> 6;
  if (lane == 0) { red[wid] = ssi; red[4 + wid] = ssj; }
  __syncthreads();
  float ti = red[0] + red[1] + red[2] + red[3];
  float tj = red[4] + red[5] + red[6] + red[7];
  float sci = brn[i] * expf(elm[i]) / sqrtf(ti + EPS_);
  float scj = brn[j] * expf(elm[j]) / sqrtf(tj + EPS_);

  for (int m0 = tid * 8; m0 < MM; m0 += 2048) {
    ushort8 pi, pj;
    #pragma unroll
    for (int q = 0; q < 8; q++) {
      int m = m0 + q;
      int p = colP[m];
      float c = colC[m], sn = colS[m];
      float vi = c * rI[m] + sn * rI[p];
      float vj = c * rJ[m] + sn * rJ[p];
      pi[q] = f2bf((cl * vi - sl * vj) * sci);
      pj[q] = f2bf((sl * vi + cl * vj) * scj);
    }
    *(ushort8*)&Wb[(size_t)i * MM + m0] = pi;
    *(ushort8*)&Wb[(size_t)j * MM + m0] = pj;
  }
}

// ---------------------------------------------------------------------------
// Kernel 4: x (f32) -> bf16
// ---------------------------------------------------------------------------
__global__ __launch_bounds__(256) void conv_x(const float* __restrict__ x,
                                              unsigned short* __restrict__ xb) {
  const size_t total = (size_t)T_N * MM / 8;
  for (size_t i = (size_t)blockIdx.x * 256 + threadIdx.x; i < total; i += 2048ull * 256ull) {
    const float* s = x + i * 8;
    f32x4 v0 = *(const f32x4*)s;
    f32x4 v1 = *(const f32x4*)(s + 4);
    ushort8 p;
    p[0] = f2bf(v0.x); p[1] = f2bf(v0.y); p[2] = f2bf(v0.z); p[3] = f2bf(v0.w);
    p[4] = f2bf(v1.x); p[5] = f2bf(v1.y); p[6] = f2bf(v1.z); p[7] = f2bf(v1.w);
    *(ushort8*)(xb + i * 8) = p;
  }
}

// ---------------------------------------------------------------------------
// global->LDS async staging helper (16B, linear LDS dest)
// ---------------------------------------------------------------------------
typedef const __attribute__((address_space(1))) unsigned int* as1_u32p;
typedef __attribute__((address_space(3))) unsigned int* as3_u32p;

__device__ __forceinline__ void gl_lds16(const void* g, void* l) {
  __builtin_amdgcn_global_load_lds((as1_u32p)g, (as3_u32p)l, 16, 0, 0);
}

// ---------------------------------------------------------------------------
// Kernel 5a: 256x256 GEMM — 3-phase kk-split schedule (r7 skeleton, tuned).
//   BK=64, 8 waves (2Mx4N), per-wave 128x64, acc[8][4], 16x16x32 bf16 MFMA.
//   LDS 128 KiB dbuf.  Per K-tile, 3 phases, 6 barriers:
//    p1: read bfA(k0),afA(k0) | bfA(k1),afA(k1) | stage B1(t+1)
//        -> bar -> lgkm(6) -> 8 MFMA(k0) -> lgkm(0) -> 8 MFMA(k1) -> bar
//    p2: read afB(k0) | afB(k1) | stage A0(t+2)
//        -> bar -> lgkm(4) -> 8 MFMA -> lgkm(0) -> 8 MFMA -> bar
//    p3: read bfB(k0) | bfB(k1) | stage A1+B0(t+2) | vmcnt(6)
//        -> bar -> lgkm(2) -> 8 -> lgkm(0) -> 8 + 16 (afA held regs) -> bar
//   FIFO ledger: outstanding at p3 gate = 14; vmcnt(6) retires exactly
//   through B1(t+1) => tile t+1 fully landed.  WAR: each staged region's
//   last LDS read >= 1 barrier earlier (Q4 uses held afA registers).
//   Swizzle (r2-verified, 0-conflict): stage src col-group ^= (row&7);
//   read byte addr: row*128 + ((kk*64+lg*16) ^ ((lr&7)<<4)).
// ---------------------------------------------------------------------------
constexpr int GBM = 256, GBN = 256, GBK = 64;
constexpr int NTK = MM / GBK;              // 64 K-tiles
constexpr int BUFB = GBM * GBK * 2;        // 32 KiB per operand per buffer

#define SB0() __builtin_amdgcn_sched_barrier(0)
#define BAR() __builtin_amdgcn_s_barrier()
#define LGKM(N) do { asm volatile("s_waitcnt lgkmcnt(" #N ")" ::: "memory"); \
                     SB0(); } while (0)

#define RD_A4K(DST, AB, MIH, KK)                                              \
  _Pragma("unroll") for (int i_ = 0; i_ < 4; ++i_)                            \
    DST[i_][KK] = *(const bf16x8*)((AB) + arow0 + ((MIH) * 4 + i_) * 2048     \
                                    + (((KK) * 64 + lg * 16) ^ sw));

#define RD_B2K(DST, BB, NIH, KK)                                              \
  _Pragma("unroll") for (int n_ = 0; n_ < 2; ++n_)                            \
    DST[n_][KK] = *(const bf16x8*)((BB) + brow0 + ((NIH) * 2 + n_) * 2048     \
                                    + (((KK) * 64 + lg * 16) ^ sw));

#define QMF8(AF, BF, MI0, NI0, KK)                                            \
  __builtin_amdgcn_s_setprio(1);                                              \
  _Pragma("unroll") for (int i_ = 0; i_ < 4; ++i_)                            \
  _Pragma("unroll") for (int n_ = 0; n_ < 2; ++n_)                            \
    acc[(MI0) + i_][(NI0) + n_] = __builtin_amdgcn_mfma_f32_16x16x32_bf16(    \
        AF[i_][KK], BF[n_][KK], acc[(MI0) + i_][(NI0) + n_], 0, 0, 0);        \
  __builtin_amdgcn_s_setprio(0);

#define STG_A(KOF, BUF, H)                                                    \
  _Pragma("unroll") for (int l_ = 2 * (H); l_ < 2 * (H) + 2; ++l_)            \
    gl_lds16(sA + (size_t)l_ * (64 * MM) + (KOF),                             \
             ldsA + (BUF) * BUFB + dstb + l_ * 8192);
#define STG_B(KOF, BUF, H)                                                    \
  _Pragma("unroll") for (int l_ = 2 * (H); l_ < 2 * (H) + 2; ++l_)            \
    gl_lds16(sB + (size_t)l_ * (64 * MM) + (KOF),                             \
             ldsB + (BUF) * BUFB + dstb + l_ * 8192);

#define GATE6  asm volatile("s_waitcnt vmcnt(6)" ::: "memory")
#define GATE0v asm volatile("s_waitcnt vmcnt(0)" ::: "memory")
#define GNONE  do { } while (0)

#define TILE3(T, BB, DOB1, DOA2, GATEK)                                       \
  {                                                                           \
    const char* Ab_ = ldsA + (BB) * BUFB;                                     \
    const char* Bb_ = ldsB + (BB) * BUFB;                                     \
    bf16x8 afA[4][2], afB[4][2], bfA[2][2], bfB[2][2];                        \
    /* ---- phase 1: Q1 = A0 x B0 ---- */                                     \
    RD_B2K(bfA, Bb_, 0, 0);                                                   \
    RD_A4K(afA, Ab_, 0, 0);                                                   \
    SB0();                                                                    \
    RD_B2K(bfA, Bb_, 0, 1);                                                   \
    RD_A4K(afA, Ab_, 0, 1);                                                   \
    SB0();                                                                    \
    if (DOB1) { STG_B(((T) + 1) * GBK, (BB) ^ 1, 1); }                        \
    BAR();                                                                    \
    LGKM(6);                                                                  \
    QMF8(afA, bfA, 0, 0, 0);                                                  \
    LGKM(0);                                                                  \
    QMF8(afA, bfA, 0, 0, 1);                                                  \
    BAR();                                                                    \
    /* ---- phase 2: Q2 = A1 x B0 ---- */                                     \
    RD_A4K(afB, Ab_, 1, 0);                                                   \
    SB0();                                                                    \
    RD_A4K(afB, Ab_, 1, 1);                                                   \
    SB0();                                                                    \
    if (DOA2) { STG_A(((T) + 2) * GBK, (BB), 0); }                            \
    BAR();                                                                    \
    LGKM(4);                                                                  \
    QMF8(afB, bfA, 4, 0, 0);                                                  \
    LGKM(0);                                                                  \
    QMF8(afB, bfA, 4, 0, 1);                                                  \
    BAR();                                                                    \
    /* ---- phase 3: Q3 = A1 x B1, Q4 = A0(held) x B1 ---- */                 \
    RD_B2K(bfB, Bb_, 1, 0);                                                   \
    SB0();                                                                    \
    RD_B2K(bfB, Bb_, 1, 1);                                                   \
    SB0();                                                                    \
    if (DOA2) { STG_A(((T) + 2) * GBK, (BB), 1);                              \
                STG_B(((T) + 2) * GBK, (BB), 0); }                            \
    GATEK;                                                                    \
    BAR();                                                                    \
    LGKM(2);                                                                  \
    QMF8(afB, bfB, 4, 2, 0);                                                  \
    LGKM(0);                                                                  \
    QMF8(afB, bfB, 4, 2, 1);                                                  \
    QMF8(afA, bfB, 0, 2, 0);                                                  \
    QMF8(afA, bfB, 0, 2, 1);                                                  \
    BAR();                                                                    \
  }

__global__ __launch_bounds__(512, 2) void gemm8(
    const unsigned short* __restrict__ xb,
    const unsigned short* __restrict__ wb,
    const float* __restrict__ bias,
    float* __restrict__ C)
{
  __shared__ __align__(16) unsigned short As[2 * GBM * GBK];  // 64 KiB
  __shared__ __align__(16) unsigned short Bs[2 * GBN * GBK];  // 64 KiB
  char* ldsA = (char*)As;
  char* ldsB = (char*)Bs;

  // grid = 512 = 32 (tm) x 16 (tn); XCD swizzle, tm-fast within an XCD so
  // consecutive blocks on one XCD share the same B panel (tn).
  int bid = blockIdx.x;
  int swz = (bid & 7) * 64 + (bid >> 3);
  int tm = swz & 31, tn = swz >> 5;
  const int trow0 = tm * GBM;
  const int tcol0 = tn * GBN;

  int tid  = threadIdx.x;
  int lane = tid & 63;
  int wid  = tid >> 6;
  int wr = wid >> 2, wc = wid & 3;   // wave coords: 2 x 4
  int lr = lane & 15;                // fragment row/col
  int lg = lane >> 4;                // k-group (8 bf16 = 16B)
  const int sw = (lr & 7) << 4;      // swizzle byte term
  const int arow0 = (wr * 128 + lr) * 128;  // A row base bytes
  const int brow0 = (wc * 64  + lr) * 128;  // B row base bytes

  // staging geometry: granule l covers rows r0 + 64*l; const col group
  const int r0   = tid >> 3;
  const int colg = (tid & 7) ^ (r0 & 7);
  const unsigned short* sA = xb + (size_t)(trow0 + r0) * MM + colg * 8;
  const unsigned short* sB = wb + (size_t)(tcol0 + r0) * MM + colg * 8;
  const int dstb = tid * 16;

  f32x4 acc[8][4];
  #pragma unroll
  for (int i = 0; i < 8; i++)
    #pragma unroll
    for (int j = 0; j < 4; j++) {
      f32x4 z = {0.f, 0.f, 0.f, 0.f};
      acc[i][j] = z;
    }

  // ---- prologue: t0 all 4 halves -> buf0; t1 A0,A1,B0 -> buf1 ----
  STG_A(0, 0, 0); STG_A(0, 0, 1); STG_B(0, 0, 0); STG_B(0, 0, 1);
  STG_A(GBK, 1, 0); STG_A(GBK, 1, 1); STG_B(GBK, 1, 0);
  asm volatile("s_waitcnt vmcnt(6)" ::: "memory");  // retire t0; t1 in flight
  __builtin_amdgcn_s_barrier();

  // ---- main loop: tiles 0..61 ----
  #pragma unroll 1
  for (int t = 0; t < NTK - 2; t += 2) {
    TILE3(t,     0, 1, 1, GATE6);
    TILE3(t + 1, 1, 1, 1, GATE6);
  }
  // ---- tail: tile 62 (stage B1(63), drain), tile 63 (compute only) ----
  TILE3(NTK - 2, 0, 1, 0, GATE0v);
  TILE3(NTK - 1, 1, 0, 0, GNONE);

  // ---- epilogue: C/D layout col = lane&15, row = (lane>>4)*4 + reg ----
  #pragma unroll
  for (int ni = 0; ni < 4; ++ni) {
    int col = tcol0 + wc * 64 + ni * 16 + lr;
    float bi = bias[col];
    #pragma unroll
    for (int mi = 0; mi < 8; ++mi) {
      int rr0 = trow0 + wr * 128 + mi * 16 + lg * 4;
      #pragma unroll
      for (int qq = 0; qq < 4; ++qq)
        C[(size_t)(rr0 + qq) * NN + col] = acc[mi][ni][qq] + bi;
    }
  }
}

// ---------------------------------------------------------------------------
// Kernel 5b (fallback, ws too small for xb): m97-style 128x128 GEMM with
// inline f32->bf16 A-staging.
// ---------------------------------------------------------------------------
constexpr int BM = 128, BN = 128, BK = 64;

__global__ __launch_bounds__(256) void gemm_fb(
    const float* __restrict__ xf,
    const unsigned short* __restrict__ wb, const float* __restrict__ bias,
    float* __restrict__ C)
{
  __shared__ __align__(16) unsigned short As2[BM * BK];
  __shared__ __align__(16) unsigned short Bs2[BN * BK];

  int bid = blockIdx.x;
  int swz = (bid & 7) * 256 + (bid >> 3);
  int tn = swz & 31;
  int tm = swz >> 5;

  int tid  = threadIdx.x;
  int lane = tid & 63;
  int wid  = tid >> 6;
  int wr = wid >> 1, wc = wid & 1;
  int lr = lane & 15;
  int lg = lane >> 4;

  f32x4 acc[4][4];
  #pragma unroll
  for (int i = 0; i < 4; i++)
    #pragma unroll
    for (int j = 0; j < 4; j++) {
      f32x4 z = {0.f, 0.f, 0.f, 0.f};
      acc[i][j] = z;
    }

  int srow = tid >> 3;
  int scol = (tid & 7) * 8;
  const size_t a_base = (size_t)(tm * BM) * MM;
  const size_t b_base = (size_t)(tn * BN) * MM;

  for (int k0 = 0; k0 < MM; k0 += BK) {
    #pragma unroll
    for (int c = 0; c < 4; c++) {
      int row = c * 32 + srow;
      gl_lds16(wb + b_base + (size_t)row * MM + k0 + scol,
               (char*)Bs2 + (c * 256 + wid * 64) * 16);
    }
    #pragma unroll
    for (int c = 0; c < 4; c++) {
      int row = c * 32 + srow;
      const float* s = xf + a_base + (size_t)row * MM + k0 + scol;
      f32x4 v0 = *(const f32x4*)s;
      f32x4 v1 = *(const f32x4*)(s + 4);
      ushort8 p;
      p[0] = f2bf(v0.x); p[1] = f2bf(v0.y); p[2] = f2bf(v0.z); p[3] = f2bf(v0.w);
      p[4] = f2bf(v1.x); p[5] = f2bf(v1.y); p[6] = f2bf(v1.z); p[7] = f2bf(v1.w);
      *(ushort8*)&As2[(c * 256 + tid) * 8] = p;
    }
    __syncthreads();

    #pragma unroll
    for (int kk = 0; kk < 2; kk++) {
      bf16x8 a[4], b[4];
      #pragma unroll
      for (int i = 0; i < 4; i++) {
        a[i] = *(const bf16x8*)&As2[(wr * 64 + i * 16 + lr) * BK + kk * 32 + lg * 8];
        b[i] = *(const bf16x8*)&Bs2[(wc * 64 + i * 16 + lr) * BK + kk * 32 + lg * 8];
      }
      #pragma unroll
      for (int i = 0; i < 4; i++)
        #pragma unroll
        for (int j = 0; j < 4; j++)
          acc[i][j] = __builtin_amdgcn_mfma_f32_16x16x32_bf16(a[i], b[j], acc[i][j], 0, 0, 0);
    }
    __syncthreads();
  }

  int gn0 = tn * BN + wc * 64;
  int gt0 = tm * BM + wr * 64;
  #pragma unroll
  for (int j = 0; j < 4; j++) {
    int gn = gn0 + j * 16 + lr;
    float bi = bias[gn];
    #pragma unroll
    for (int i = 0; i < 4; i++) {
      int t0 = gt0 + i * 16 + lg * 4;
      #pragma unroll
      for (int q = 0; q < 4; q++)
        C[(size_t)(t0 + q) * NN + gn] = acc[i][j][q] + bi;
    }
  }
}

// ---------------------------------------------------------------------------
extern "C" void kernel_launch(void* const* d_in, const int* in_sizes, int n_in,
                              void* d_out, int out_size, void* d_ws, size_t ws_size,
                              hipStream_t stream)
{
  const float* x    = (const float*)d_in[0];
  const float* W    = (const float*)d_in[1];
  const float* bias = (const float*)d_in[2];
  const float* thL  = (const float*)d_in[3];
  const float* thR  = (const float*)d_in[4];
  const float* elm  = (const float*)d_in[5];
  const float* brn  = (const float*)d_in[6];
  const int*   prL  = (const int*)d_in[7];
  const int*   prR  = (const int*)d_in[8];
  float* out = (float*)d_out;

  char* ws = (char*)d_ws;
  unsigned short* Wb = (unsigned short*)ws;          // N*M bf16 = 33.5 MB
  size_t off = (size_t)NN * MM * 2;
  float* colC = (float*)(ws + off); off += MM * 4;
  float* colS = (float*)(ws + off); off += MM * 4;
  int*   colP = (int*)  (ws + off); off += MM * 4;
  unsigned short* xb = (unsigned short*)(ws + off);  // T*M bf16 = 67 MB
  bool use_xb = ws_size >= off + (size_t)T_N * MM * 2;

  init_cols <<<16, 256, 0, stream>>>(colC, colS, colP);
  build_cols<<< 8, 256, 0, stream>>>(thR, prR, colC, colS, colP);
  weff_pair <<<S_L, 256, 0, stream>>>(W, brn, elm, thL, prL, colC, colS, colP, Wb);

  if (use_xb) {
    conv_x<<<2048, 256, 0, stream>>>(x, xb);
    gemm8<<<512, 512, 0, stream>>>(xb, Wb, bias, out);
  } else {
    gemm_fb<<<2048, 256, 0, stream>>>(x, Wb, bias, out);
  }
}

// Round 9
// 301.681 us; speedup vs baseline: 1.1336x; 1.0544x over previous
//
#include <hip/hip_runtime.h>
#include <cstdint>
#include <cstddef>

// Problem constants
constexpr int T_N = 8192;   // rows of x / out
constexpr int MM  = 4096;   // K (cols of x, cols of W)
constexpr int NN  = 4096;   // rows of W / cols of out
constexpr int S_L = 2048;
constexpr int S_R = 2048;
constexpr float EPS_ = 1e-6f;

typedef float  f32x4   __attribute__((ext_vector_type(4)));
typedef __bf16 bf16x8  __attribute__((ext_vector_type(8)));
typedef unsigned short ushort8 __attribute__((ext_vector_type(8)));

__device__ __forceinline__ unsigned short f2bf(float f) {
  unsigned int u = __float_as_uint(f);
  u += 0x7FFFu + ((u >> 16) & 1u);   // round-to-nearest-even
  return (unsigned short)(u >> 16);
}

// ---------------------------------------------------------------------------
// Kernel 1: identity column maps
// ---------------------------------------------------------------------------
__global__ void init_cols(float* colC, float* colS, int* colP) {
  int i = blockIdx.x * blockDim.x + threadIdx.x;
  if (i < MM) { colC[i] = 1.f; colS[i] = 0.f; colP[i] = i; }
}

// ---------------------------------------------------------------------------
// Kernel 2: column rotation maps from (pairs_R, theta_R).
// ---------------------------------------------------------------------------
__global__ void build_cols(const float* __restrict__ thR, const int* __restrict__ prR,
                           float* colC, float* colS, int* colP) {
  int s = blockIdx.x * blockDim.x + threadIdx.x;
  if (s < S_R) {
    int i = prR[2*s], j = prR[2*s+1];
    float c = cosf(thR[s]), sn = sinf(thR[s]);
    colC[i] = c; colS[i] = -sn; colP[i] = j;
    colC[j] = c; colS[j] =  sn; colP[j] = i;
  }
}

// ---------------------------------------------------------------------------
// Kernel 3 (fused): bid < S_L  -> W_eff pair build (rows i,j of pair s=bid)
//                   bid >= S_L -> x f32->bf16 conversion chunk
// Both paths are HBM-bound; fusing overlaps W reads with x reads and saves
// one dispatch round-trip.
// ---------------------------------------------------------------------------
__global__ __launch_bounds__(256) void weff_conv(
    const float* __restrict__ W, const float* __restrict__ brn, const float* __restrict__ elm,
    const float* __restrict__ thL, const int* __restrict__ prL,
    const float* __restrict__ colC, const float* __restrict__ colS, const int* __restrict__ colP,
    unsigned short* __restrict__ Wb,
    const float* __restrict__ x, unsigned short* __restrict__ xb)
{
  __shared__ __align__(16) float rI[MM];
  __shared__ __align__(16) float rJ[MM];
  __shared__ float red[8];

  int bid = blockIdx.x;
  int tid = threadIdx.x;

  if (bid >= S_L) {
    // ---- conv path: x -> bf16, grid-stride over 2048 virtual blocks ----
    const size_t total = (size_t)T_N * MM / 8;
    for (size_t i = (size_t)(bid - S_L) * 256 + tid; i < total; i += 2048ull * 256ull) {
      const float* s = x + i * 8;
      f32x4 v0 = *(const f32x4*)s;
      f32x4 v1 = *(const f32x4*)(s + 4);
      ushort8 p;
      p[0] = f2bf(v0.x); p[1] = f2bf(v0.y); p[2] = f2bf(v0.z); p[3] = f2bf(v0.w);
      p[4] = f2bf(v1.x); p[5] = f2bf(v1.y); p[6] = f2bf(v1.z); p[7] = f2bf(v1.w);
      *(ushort8*)(xb + i * 8) = p;
    }
    return;
  }

  // ---- weff pair path ----
  int s = bid;
  int i = prL[2*s], j = prL[2*s+1];
  float cl = cosf(thL[s]), sl = sinf(thL[s]);
  const float* Wi = W + (size_t)i * MM;
  const float* Wj = W + (size_t)j * MM;

  for (int m = tid * 4; m < MM; m += 1024) {
    *(f32x4*)&rI[m] = *(const f32x4*)&Wi[m];
    *(f32x4*)&rJ[m] = *(const f32x4*)&Wj[m];
  }
  __syncthreads();

  float ssi = 0.f, ssj = 0.f;
  for (int m = tid; m < MM; m += 256) {
    int p = colP[m];
    float c = colC[m], sn = colS[m];
    float vi = c * rI[m] + sn * rI[p];
    float vj = c * rJ[m] + sn * rJ[p];
    float ei = cl * vi - sl * vj;
    float ej = sl * vi + cl * vj;
    ssi += ei * ei;
    ssj += ej * ej;
  }
  #pragma unroll
  for (int o = 32; o; o >>= 1) { ssi += __shfl_xor(ssi, o); ssj += __shfl_xor(ssj, o); }
  int lane = tid & 63, wid = tid >> 6;
  if (lane == 0) { red[wid] = ssi; red[4 + wid] = ssj; }
  __syncthreads();
  float ti = red[0] + red[1] + red[2] + red[3];
  float tj = red[4] + red[5] + red[6] + red[7];
  float sci = brn[i] * expf(elm[i]) / sqrtf(ti + EPS_);
  float scj = brn[j] * expf(elm[j]) / sqrtf(tj + EPS_);

  for (int m0 = tid * 8; m0 < MM; m0 += 2048) {
    ushort8 pi, pj;
    #pragma unroll
    for (int q = 0; q < 8; q++) {
      int m = m0 + q;
      int p = colP[m];
      float c = colC[m], sn = colS[m];
      float vi = c * rI[m] + sn * rI[p];
      float vj = c * rJ[m] + sn * rJ[p];
      pi[q] = f2bf((cl * vi - sl * vj) * sci);
      pj[q] = f2bf((sl * vi + cl * vj) * scj);
    }
    *(ushort8*)&Wb[(size_t)i * MM + m0] = pi;
    *(ushort8*)&Wb[(size_t)j * MM + m0] = pj;
  }
}

// ---------------------------------------------------------------------------
// global->LDS async staging helper (16B, linear LDS dest)
// ---------------------------------------------------------------------------
typedef const __attribute__((address_space(1))) unsigned int* as1_u32p;
typedef __attribute__((address_space(3))) unsigned int* as3_u32p;

__device__ __forceinline__ void gl_lds16(const void* g, void* l) {
  __builtin_amdgcn_global_load_lds((as1_u32p)g, (as3_u32p)l, 16, 0, 0);
}

// ---------------------------------------------------------------------------
// Kernel 5a: 256x256 GEMM — exact m201 8-phase slot schedule.
//   BK=64, 8 waves (2Mx4N), per-wave 128x64, acc[8][4], 16x16x32 bf16 MFMA.
//   LDS 128 KiB dbuf.  8 phases per 2 K-tiles; each phase:
//     {ds_reads(12/8/4/0), stage ONE half-tile (2 gl_lds)} -> [lgkm(8) if 12]
//     -> bar -> lgkm(0) -> setprio(1) 16 MFMA setprio(0) -> bar
//   Stage slots (tile t even, buffers: t&1):
//     P1: B1(t+1)  P2: A0(t+2)  P3: A1(t+2)  P4: B0(t+2)  [vmcnt(6)]
//     P5: B1(t+2)  P6: A0(t+3)  P7: A1(t+3)  P8: B0(t+3)  [vmcnt(6)]
//   Ledger: each gate leaves exactly 3 half-tiles in flight; a tile is fully
//   retired at the gate before the phase that reads it (RAW).  Every stage
//   targets the region whose last ds_read completed one phase-barrier
//   earlier (WAR).  Quadrants: P1 Q1=A0xB0, P2 Q2=A1xB0, P3 Q3=A1xB1,
//   P4 Q4=A0xB1 (held regs, zero reads -> LDS catch-up window).
//   Swizzle (r2-verified, 0 conflicts): stage src col-group ^= (row&7);
//   read byte addr: row*128 + ((kk*64+lg*16) ^ ((lr&7)<<4)).
// ---------------------------------------------------------------------------
constexpr int GBM = 256, GBN = 256, GBK = 64;
constexpr int NTK = MM / GBK;              // 64 K-tiles
constexpr int BUFB = GBM * GBK * 2;        // 32 KiB per operand per buffer

#define SB0() __builtin_amdgcn_sched_barrier(0)
#define BAR() __builtin_amdgcn_s_barrier()
#define LGKM(N) do { asm volatile("s_waitcnt lgkmcnt(" #N ")" ::: "memory"); \
                     SB0(); } while (0)

#define RD_A8(DST, AB, MIH)                                                   \
  _Pragma("unroll") for (int i_ = 0; i_ < 4; ++i_)                            \
  _Pragma("unroll") for (int k_ = 0; k_ < 2; ++k_)                            \
    DST[i_][k_] = *(const bf16x8*)((AB) + arow0 + ((MIH) * 4 + i_) * 2048     \
                                    + ((k_ * 64 + lg * 16) ^ sw));

#define RD_B4(DST, BB, NIH)                                                   \
  _Pragma("unroll") for (int n_ = 0; n_ < 2; ++n_)                            \
  _Pragma("unroll") for (int k_ = 0; k_ < 2; ++k_)                            \
    DST[n_][k_] = *(const bf16x8*)((BB) + brow0 + ((NIH) * 2 + n_) * 2048     \
                                    + ((k_ * 64 + lg * 16) ^ sw));

#define QMF(AF, BF, MI0, NI0)                                                 \
  __builtin_amdgcn_s_setprio(1);                                              \
  _Pragma("unroll") for (int k_ = 0; k_ < 2; ++k_)                            \
  _Pragma("unroll") for (int i_ = 0; i_ < 4; ++i_)                            \
  _Pragma("unroll") for (int n_ = 0; n_ < 2; ++n_)                            \
    acc[(MI0) + i_][(NI0) + n_] = __builtin_amdgcn_mfma_f32_16x16x32_bf16(    \
        AF[i_][k_], BF[n_][k_], acc[(MI0) + i_][(NI0) + n_], 0, 0, 0);        \
  __builtin_amdgcn_s_setprio(0);

#define STG_A(KOF, BUF, H)                                                    \
  _Pragma("unroll") for (int l_ = 2 * (H); l_ < 2 * (H) + 2; ++l_)            \
    gl_lds16(sA + (size_t)l_ * (64 * MM) + (KOF),                             \
             ldsA + (BUF) * BUFB + dstb + l_ * 8192);
#define STG_B(KOF, BUF, H)                                                    \
  _Pragma("unroll") for (int l_ = 2 * (H); l_ < 2 * (H) + 2; ++l_)            \
    gl_lds16(sB + (size_t)l_ * (64 * MM) + (KOF),                             \
             ldsB + (BUF) * BUFB + dstb + l_ * 8192);

#define GATE6  asm volatile("s_waitcnt vmcnt(6)" ::: "memory")
#define GATE0v asm volatile("s_waitcnt vmcnt(0)" ::: "memory")
#define GNONE  do { } while (0)
#define NOST   do { } while (0)

// One K-tile = 4 phases.  ST1..ST4 are half-tile stage statements (or NOST);
// GATE fires in P4 before its barrier.
#define TILE4(T, BB, ST1, ST2, ST3, ST4, GATE)                                \
  {                                                                           \
    const char* Ab_ = ldsA + (BB) * BUFB;                                     \
    const char* Bb_ = ldsB + (BB) * BUFB;                                     \
    bf16x8 a0[4][2], a1[4][2], b0[2][2], b1[2][2];                            \
    /* P1: 12 reads; stage ST1; lgkm(8); Q1 = A0 x B0 */                      \
    RD_B4(b0, Bb_, 0);                                                        \
    RD_A8(a0, Ab_, 0);                                                        \
    SB0();                                                                    \
    ST1;                                                                      \
    LGKM(8);                                                                  \
    BAR();                                                                    \
    LGKM(0);                                                                  \
    QMF(a0, b0, 0, 0);                                                        \
    BAR();                                                                    \
    /* P2: 8 reads; stage ST2; Q2 = A1 x B0 */                                \
    RD_A8(a1, Ab_, 1);                                                        \
    SB0();                                                                    \
    ST2;                                                                      \
    BAR();                                                                    \
    LGKM(0);                                                                  \
    QMF(a1, b0, 4, 0);                                                        \
    BAR();                                                                    \
    /* P3: 4 reads; stage ST3; Q3 = A1 x B1 */                                \
    RD_B4(b1, Bb_, 1);                                                        \
    SB0();                                                                    \
    ST3;                                                                      \
    BAR();                                                                    \
    LGKM(0);                                                                  \
    QMF(a1, b1, 4, 2);                                                        \
    BAR();                                                                    \
    /* P4: 0 reads; stage ST4; gate; Q4 = A0 x B1 (held regs) */              \
    ST4;                                                                      \
    GATE;                                                                     \
    BAR();                                                                    \
    QMF(a0, b1, 0, 2);                                                        \
    BAR();                                                                    \
  }

__global__ __launch_bounds__(512, 2) void gemm8(
    const unsigned short* __restrict__ xb,
    const unsigned short* __restrict__ wb,
    const float* __restrict__ bias,
    float* __restrict__ C)
{
  __shared__ __align__(16) unsigned short As[2 * GBM * GBK];  // 64 KiB
  __shared__ __align__(16) unsigned short Bs[2 * GBN * GBK];  // 64 KiB
  char* ldsA = (char*)As;
  char* ldsB = (char*)Bs;

  // grid = 512 = 32 (tm) x 16 (tn); XCD swizzle, tn-fast within an XCD
  // (r7 layout: FETCH ~295 MB; r8's tm-fast doubled it).
  int bid = blockIdx.x;
  int swz = (bid & 7) * 64 + (bid >> 3);
  int tn = swz & 15, tm = swz >> 4;
  const int trow0 = tm * GBM;
  const int tcol0 = tn * GBN;

  int tid  = threadIdx.x;
  int lane = tid & 63;
  int wid  = tid >> 6;
  int wr = wid >> 2, wc = wid & 3;   // wave coords: 2 x 4
  int lr = lane & 15;                // fragment row/col
  int lg = lane >> 4;                // k-group (8 bf16 = 16B)
  const int sw = (lr & 7) << 4;      // swizzle byte term
  const int arow0 = (wr * 128 + lr) * 128;  // A row base bytes
  const int brow0 = (wc * 64  + lr) * 128;  // B row base bytes

  // staging geometry: granule l covers rows r0 + 64*l; const col group
  const int r0   = tid >> 3;
  const int colg = (tid & 7) ^ (r0 & 7);
  const unsigned short* sA = xb + (size_t)(trow0 + r0) * MM + colg * 8;
  const unsigned short* sB = wb + (size_t)(tcol0 + r0) * MM + colg * 8;
  const int dstb = tid * 16;

  f32x4 acc[8][4];
  #pragma unroll
  for (int i = 0; i < 8; i++)
    #pragma unroll
    for (int j = 0; j < 4; j++) {
      f32x4 z = {0.f, 0.f, 0.f, 0.f};
      acc[i][j] = z;
    }

  // ---- prologue: t0 full -> buf0; t1 A0,A1,B0 -> buf1 (7 half-tiles);
  //      vmcnt(6) retires t0's 4, leaves t1's 3 in flight ----
  STG_A(0, 0, 0); STG_A(0, 0, 1); STG_B(0, 0, 0); STG_B(0, 0, 1);
  STG_A(GBK, 1, 0); STG_A(GBK, 1, 1); STG_B(GBK, 1, 0);
  asm volatile("s_waitcnt vmcnt(6)" ::: "memory");
  __builtin_amdgcn_s_barrier();

  // ---- main loop: iters (t, t+1), t = 0..60 step 2; stages t+2, t+3 ----
  #pragma unroll 1
  for (int t = 0; t < NTK - 2; t += 2) {
    TILE4(t, 0,
          STG_B((t + 1) * GBK, 1, 1),   // P1: B1(t+1)
          STG_A((t + 2) * GBK, 0, 0),   // P2: A0(t+2)
          STG_A((t + 2) * GBK, 0, 1),   // P3: A1(t+2)
          STG_B((t + 2) * GBK, 0, 0),   // P4: B0(t+2)
          GATE6);
    TILE4(t + 1, 1,
          STG_B((t + 2) * GBK, 0, 1),   // P5: B1(t+2)
          STG_A((t + 3) * GBK, 1, 0),   // P6: A0(t+3)
          STG_A((t + 3) * GBK, 1, 1),   // P7: A1(t+3)
          STG_B((t + 3) * GBK, 1, 0),   // P8: B0(t+3)
          GATE6);
  }
  // ---- tail: tile 62 stages only B1(63), drains; tile 63 compute-only ----
  TILE4(NTK - 2, 0,
        STG_B((NTK - 1) * GBK, 1, 1),   // B1(63)
        NOST, NOST, NOST, GATE0v);
  TILE4(NTK - 1, 1, NOST, NOST, NOST, NOST, GNONE);

  // ---- epilogue: C/D layout col = lane&15, row = (lane>>4)*4 + reg ----
  #pragma unroll
  for (int ni = 0; ni < 4; ++ni) {
    int col = tcol0 + wc * 64 + ni * 16 + lr;
    float bi = bias[col];
    #pragma unroll
    for (int mi = 0; mi < 8; ++mi) {
      int rr0 = trow0 + wr * 128 + mi * 16 + lg * 4;
      #pragma unroll
      for (int qq = 0; qq < 4; ++qq)
        C[(size_t)(rr0 + qq) * NN + col] = acc[mi][ni][qq] + bi;
    }
  }
}

// ---------------------------------------------------------------------------
// Kernel 5b (fallback, ws too small for xb): m97-style 128x128 GEMM with
// inline f32->bf16 A-staging.
// ---------------------------------------------------------------------------
constexpr int BM = 128, BN = 128, BK = 64;

__global__ __launch_bounds__(256) void gemm_fb(
    const float* __restrict__ xf,
    const unsigned short* __restrict__ wb, const float* __restrict__ bias,
    float* __restrict__ C)
{
  __shared__ __align__(16) unsigned short As2[BM * BK];
  __shared__ __align__(16) unsigned short Bs2[BN * BK];

  int bid = blockIdx.x;
  int swz = (bid & 7) * 256 + (bid >> 3);
  int tn = swz & 31;
  int tm = swz >> 5;

  int tid  = threadIdx.x;
  int lane = tid & 63;
  int wid  = tid >> 6;
  int wr = wid >> 1, wc = wid & 1;
  int lr = lane & 15;
  int lg = lane >> 4;

  f32x4 acc[4][4];
  #pragma unroll
  for (int i = 0; i < 4; i++)
    #pragma unroll
    for (int j = 0; j < 4; j++) {
      f32x4 z = {0.f, 0.f, 0.f, 0.f};
      acc[i][j] = z;
    }

  int srow = tid >> 3;
  int scol = (tid & 7) * 8;
  const size_t a_base = (size_t)(tm * BM) * MM;
  const size_t b_base = (size_t)(tn * BN) * MM;

  for (int k0 = 0; k0 < MM; k0 += BK) {
    #pragma unroll
    for (int c = 0; c < 4; c++) {
      int row = c * 32 + srow;
      gl_lds16(wb + b_base + (size_t)row * MM + k0 + scol,
               (char*)Bs2 + (c * 256 + wid * 64) * 16);
    }
    #pragma unroll
    for (int c = 0; c < 4; c++) {
      int row = c * 32 + srow;
      const float* s = xf + a_base + (size_t)row * MM + k0 + scol;
      f32x4 v0 = *(const f32x4*)s;
      f32x4 v1 = *(const f32x4*)(s + 4);
      ushort8 p;
      p[0] = f2bf(v0.x); p[1] = f2bf(v0.y); p[2] = f2bf(v0.z); p[3] = f2bf(v0.w);
      p[4] = f2bf(v1.x); p[5] = f2bf(v1.y); p[6] = f2bf(v1.z); p[7] = f2bf(v1.w);
      *(ushort8*)&As2[(c * 256 + tid) * 8] = p;
    }
    __syncthreads();

    #pragma unroll
    for (int kk = 0; kk < 2; kk++) {
      bf16x8 a[4], b[4];
      #pragma unroll
      for (int i = 0; i < 4; i++) {
        a[i] = *(const bf16x8*)&As2[(wr * 64 + i * 16 + lr) * BK + kk * 32 + lg * 8];
        b[i] = *(const bf16x8*)&Bs2[(wc * 64 + i * 16 + lr) * BK + kk * 32 + lg * 8];
      }
      #pragma unroll
      for (int i = 0; i < 4; i++)
        #pragma unroll
        for (int j = 0; j < 4; j++)
          acc[i][j] = __builtin_amdgcn_mfma_f32_16x16x32_bf16(a[i], b[j], acc[i][j], 0, 0, 0);
    }
    __syncthreads();
  }

  int gn0 = tn * BN + wc * 64;
  int gt0 = tm * BM + wr * 64;
  #pragma unroll
  for (int j = 0; j < 4; j++) {
    int gn = gn0 + j * 16 + lr;
    float bi = bias[gn];
    #pragma unroll
    for (int i = 0; i < 4; i++) {
      int t0 = gt0 + i * 16 + lg * 4;
      #pragma unroll
      for (int q = 0; q < 4; q++)
        C[(size_t)(t0 + q) * NN + gn] = acc[i][j][q] + bi;
    }
  }
}

// ---------------------------------------------------------------------------
extern "C" void kernel_launch(void* const* d_in, const int* in_sizes, int n_in,
                              void* d_out, int out_size, void* d_ws, size_t ws_size,
                              hipStream_t stream)
{
  const float* x    = (const float*)d_in[0];
  const float* W    = (const float*)d_in[1];
  const float* bias = (const float*)d_in[2];
  const float* thL  = (const float*)d_in[3];
  const float* thR  = (const float*)d_in[4];
  const float* elm  = (const float*)d_in[5];
  const float* brn  = (const float*)d_in[6];
  const int*   prL  = (const int*)d_in[7];
  const int*   prR  = (const int*)d_in[8];
  float* out = (float*)d_out;

  char* ws = (char*)d_ws;
  unsigned short* Wb = (unsigned short*)ws;          // N*M bf16 = 33.5 MB
  size_t off = (size_t)NN * MM * 2;
  float* colC = (float*)(ws + off); off += MM * 4;
  float* colS = (float*)(ws + off); off += MM * 4;
  int*   colP = (int*)  (ws + off); off += MM * 4;
  unsigned short* xb = (unsigned short*)(ws + off);  // T*M bf16 = 67 MB
  bool use_xb = ws_size >= off + (size_t)T_N * MM * 2;

  init_cols <<<16, 256, 0, stream>>>(colC, colS, colP);
  build_cols<<< 8, 256, 0, stream>>>(thR, prR, colC, colS, colP);

  if (use_xb) {
    weff_conv<<<S_L + 2048, 256, 0, stream>>>(W, brn, elm, thL, prL,
                                              colC, colS, colP, Wb, x, xb);
    gemm8<<<512, 512, 0, stream>>>(xb, Wb, bias, out);
  } else {
    weff_conv<<<S_L, 256, 0, stream>>>(W, brn, elm, thL, prL,
                                       colC, colS, colP, Wb, x, xb);
    gemm_fb<<<2048, 256, 0, stream>>>(x, Wb, bias, out);
  }
}